// Round 6
// baseline (1092.713 us; speedup 1.0000x reference)
//
#include <hip/hip_runtime.h>
#include <hip/hip_fp16.h>

#define B_ 512
#define T_ 512
#define H_ 64
#define K_ 4

// ws layout:
//   wh   f16 [K*3*H*H]   @ 0        (98304 B)
//   wi   f16 [3*H*H]     @ 98304    (24576 B)
//   wo16 f16 [2*H]       @ 122880   (256 B)
//   flag int             @ 123136
//   xh16 f16 [B*T*H]     @ 131072   (33554432 B)   [BIG only]
//   h16  f16 [B*T*H]     @ 33685504 (33554432 B)   [BIG only]
#define WS_WI_OFF    98304
#define WS_WO_OFF    122880
#define WS_FLAG_OFF  123136
#define WS_XH_OFF    131072
#define WS_H16_OFF   33685504
#define WS_BIG_NEED  67239936ull

typedef _Float16 half2_t __attribute__((ext_vector_type(2)));

union Q { uint4 u; half2_t h[4]; };  // 16 B = 4 packed half2

__device__ __forceinline__ float fdot2f(half2_t a, half2_t b, float c) {
#if __has_builtin(__builtin_amdgcn_fdot2)
    return __builtin_amdgcn_fdot2(a, b, c, false);
#else
    return fmaf((float)a[0], (float)b[0], fmaf((float)a[1], (float)b[1], c));
#endif
}

__device__ __forceinline__ half2_t pkh2(float a, float b) {
    return __builtin_bit_cast(half2_t, __builtin_amdgcn_cvt_pkrtz(a, b));
}

// Detect whether mask buffer is 1-byte bools or int32 0/1 (little-endian).
__global__ void detect_mask_kernel(const unsigned char* __restrict__ mb, int* __restrict__ flag) {
    __shared__ int cnt;
    if (threadIdx.x == 0) cnt = 0;
    __syncthreads();
    int c = 0;
    for (int i = threadIdx.x; i < 4096; i += blockDim.x)
        if ((i & 3) != 0 && mb[i] != 0) c++;
    atomicAdd(&cnt, c);
    __syncthreads();
    if (threadIdx.x == 0) *flag = (cnt > 0) ? 1 : 0;  // 1 => uint8 bools, 0 => int32
}

// W_h* [K,H,H] -> wh f16 ((k*3+g)*H + i)*H + j ; W_i* -> wi (g*H+i)*H+j ; Wo -> wo16
__global__ void convert_weights_kernel(const float* __restrict__ Whr, const float* __restrict__ Whz,
                                       const float* __restrict__ Whn, const float* __restrict__ Wir,
                                       const float* __restrict__ Wiz, const float* __restrict__ Win,
                                       const float* __restrict__ Wo,
                                       __half* __restrict__ wh, __half* __restrict__ wi,
                                       __half* __restrict__ wo16) {
    int idx = blockIdx.x * 256 + threadIdx.x;
    if (idx < K_ * 3 * H_ * H_) {
        int k = idx / (3 * H_ * H_);
        int r = idx - k * (3 * H_ * H_);
        int g = r >> 12;
        int i = (r >> 6) & 63;
        int j = r & 63;
        const float* src = (g == 0) ? Whr : (g == 1) ? Whz : Whn;
        wh[idx] = __float2half(src[(k * H_ + i) * H_ + j]);
    }
    if (idx < 3 * H_ * H_) {
        int g = idx >> 12;
        int i = (idx >> 6) & 63;
        int j = idx & 63;
        const float* src = (g == 0) ? Wir : (g == 1) ? Wiz : Win;
        wi[idx] = __float2half(src[i * H_ + j]);
    }
    if (idx < 2 * H_) wo16[idx] = __float2half(Wo[idx]);
}

// x f32 -> packed f16 (8 floats per thread)
__global__ void convert_x_kernel(const float* __restrict__ xf, __half* __restrict__ xh) {
    size_t i = (size_t)blockIdx.x * 256 + threadIdx.x;   // one uint4 (8 halves) out
    if (i >= (size_t)B_ * T_ * H_ / 8) return;
    const float4* p = (const float4*)xf + 2 * i;
    float4 a = p[0], b = p[1];
    Q o;
    o.h[0] = pkh2(a.x, a.y);
    o.h[1] = pkh2(a.z, a.w);
    o.h[2] = pkh2(b.x, b.y);
    o.h[3] = pkh2(b.z, b.w);
    ((uint4*)xh)[i] = o.u;
}

// Parallel logits: one thread per (b,t): out = h16[bt,:] . wo16 rows + bias
__global__ __launch_bounds__(256)
void logits_kernel(const __half* __restrict__ h16, const __half* __restrict__ wo16,
                   const float* __restrict__ Wo_b, float* __restrict__ out) {
    const int idx = blockIdx.x * 256 + threadIdx.x;      // 0..B*T-1
    Q w0[8], w1[8], hv[8];
    const uint4* wp = (const uint4*)wo16;
#pragma unroll
    for (int q = 0; q < 8; q++) { w0[q].u = wp[q]; w1[q].u = wp[8 + q]; }
    const uint4* hp = (const uint4*)(h16 + (size_t)idx * H_);
#pragma unroll
    for (int q = 0; q < 8; q++) hv[q].u = hp[q];
    float l0 = Wo_b[0], l1 = Wo_b[1];
#pragma unroll
    for (int q = 0; q < 8; q++)
#pragma unroll
        for (int p = 0; p < 4; p++) {
            l0 = fdot2f(w0[q].h[p], hv[q].h[p], l0);
            l1 = fdot2f(w1[q].h[p], hv[q].h[p], l1);
        }
    ((float2*)out)[idx] = make_float2(l0, l1);
}

// Sequential GRU: ONE WAVE PER BATCH ELEMENT. No inter-wave coupling.
// lane = output row i; full-j matvecs via v_dot2 (96 hidden + 96 input fdot2).
// h broadcast: ds_write_b16 + 8 uniform ds_read_b128 within the wave.
// W_h[k_t] rows streamed from L2 each step (24 KB/wave/step, 98 KB/XCD resident);
// latency covered by the h-independent input projection.
// BIG: x pre-packed f16, h stored to global f16, logits in a separate kernel.
// !BIG: x packed in-loop from f32, logits via in-wave shuffles.
template <bool BIG>
__global__ __launch_bounds__(64, 1)
void gru_seq(const float* __restrict__ xf, const __half* __restrict__ xh16,
             const int* __restrict__ ctx, const unsigned char* __restrict__ maskb,
             const int* __restrict__ flagp,
             const __half* __restrict__ wh, const __half* __restrict__ wi,
             const float* __restrict__ b_ir, const float* __restrict__ b_iz,
             const float* __restrict__ b_in, const float* __restrict__ b_hr,
             const float* __restrict__ b_hz, const float* __restrict__ b_hn,
             const float* __restrict__ Wo_w, const float* __restrict__ Wo_b,
             __half* __restrict__ h16out, float* __restrict__ out) {
    __shared__ __align__(16) __half hsh[2][64];

    const int lane = threadIdx.x;    // 0..63 (one wave per block)
    const int b    = blockIdx.x;
    const int flag   = *flagp;
    const int mshift = flag ? 0 : 2;
    const int bt0 = b * T_;

    // ---- input weights: full rows, 96 VGPRs ----
    Q wirq[8], wizq[8], winq[8];
    {
        const uint4* qr = (const uint4*)(wi + (0 * H_ + lane) * H_);
        const uint4* qz = (const uint4*)(wi + (1 * H_ + lane) * H_);
        const uint4* qn = (const uint4*)(wi + (2 * H_ + lane) * H_);
#pragma unroll
        for (int q = 0; q < 8; q++) { wirq[q].u = qr[q]; wizq[q].u = qz[q]; winq[q].u = qn[q]; }
    }

    const float bir = b_ir[lane], biz = b_iz[lane], bin = b_in[lane];
    float wo0 = 0.f, wo1 = 0.f, wob0 = 0.f, wob1 = 0.f;
    if constexpr (!BIG) {
        wo0 = Wo_w[lane]; wo1 = Wo_w[64 + lane]; wob0 = Wo_b[0]; wob1 = Wo_b[1];
    }

    float hreg = 0.0f;
    Q hq[8];
#pragma unroll
    for (int q = 0; q < 8; q++) hq[q].u = make_uint4(0u, 0u, 0u, 0u);

    // ---- prologue: x(0), ctx(0), mask(0) ----
    Q xpk[8];
    if constexpr (BIG) {
        const uint4* xp = (const uint4*)(xh16 + (size_t)bt0 * H_);
#pragma unroll
        for (int q = 0; q < 8; q++) xpk[q].u = xp[q];
    } else {
        const float4* xp = (const float4*)(xf + (size_t)bt0 * H_);
#pragma unroll
        for (int q = 0; q < 8; q++) {
            float4 a = xp[2 * q], c = xp[2 * q + 1];
            xpk[q].h[0] = pkh2(a.x, a.y);
            xpk[q].h[1] = pkh2(a.z, a.w);
            xpk[q].h[2] = pkh2(c.x, c.y);
            xpk[q].h[3] = pkh2(c.z, c.w);
        }
    }
    int   kc = __builtin_amdgcn_readfirstlane(ctx[bt0]);
    float mc = maskb[(size_t)bt0 << mshift] ? 1.0f : 0.0f;

    float* outp = out + (size_t)b * T_ * 2;

#pragma unroll 1
    for (int t = 0; t < T_; t++) {
        const int bt  = bt0 + t;
        const int tn  = (t + 1 < T_) ? (t + 1) : t;
        const int btn = bt0 + tn;

        // ---- issue W_h[k_t] row loads (L2) ----
        Q whrq[8], whzq[8], whnq[8];
        {
            const uint4* pr = (const uint4*)(wh + ((size_t)((kc * 3 + 0) * H_ + lane) * H_));
            const uint4* pz = (const uint4*)(wh + ((size_t)((kc * 3 + 1) * H_ + lane) * H_));
            const uint4* pn = (const uint4*)(wh + ((size_t)((kc * 3 + 2) * H_ + lane) * H_));
#pragma unroll
            for (int q = 0; q < 8; q++) { whrq[q].u = pr[q]; whzq[q].u = pz[q]; whnq[q].u = pn[q]; }
        }
        const float bhr = b_hr[kc * H_ + lane];
        const float bhz = b_hz[kc * H_ + lane];
        const float bhn = b_hn[kc * H_ + lane];

        // ---- prefetch t+1 inputs ----
        Q xnp[8];
        float4 xnf[16];
        if constexpr (BIG) {
            const uint4* xp = (const uint4*)(xh16 + (size_t)btn * H_);
#pragma unroll
            for (int q = 0; q < 8; q++) xnp[q].u = xp[q];
        } else {
            const float4* xp = (const float4*)(xf + (size_t)btn * H_);
#pragma unroll
            for (int q = 0; q < 16; q++) xnf[q] = xp[q];
        }
        int           kn  = ctx[btn];
        unsigned char mnb = maskb[(size_t)btn << mshift];

        // ---- input projection (h-independent: covers W/L2 latency) ----
        float sir = 0.f, siz = 0.f, sin_ = 0.f;
#pragma unroll
        for (int q = 0; q < 8; q++)
#pragma unroll
            for (int p = 0; p < 4; p++) {
                sir  = fdot2f(wirq[q].h[p], xpk[q].h[p], sir);
                siz  = fdot2f(wizq[q].h[p], xpk[q].h[p], siz);
                sin_ = fdot2f(winq[q].h[p], xpk[q].h[p], sin_);
            }

        // ---- hidden matvec (full j, 96 fdot2) ----
        float shr = 0.f, shz = 0.f, shn = 0.f;
#pragma unroll
        for (int q = 0; q < 8; q++)
#pragma unroll
            for (int p = 0; p < 4; p++) {
                shr = fdot2f(whrq[q].h[p], hq[q].h[p], shr);
                shz = fdot2f(whzq[q].h[p], hq[q].h[p], shz);
                shn = fdot2f(whnq[q].h[p], hq[q].h[p], shn);
            }

        // ---- epilogue (all in-lane, no cross-lane reduce) ----
        const float ar = sir + shr + bir + bhr;
        const float az = siz + shz + biz + bhz;
        const float r  = 1.0f / (1.0f + __expf(-ar));
        const float z  = 1.0f / (1.0f + __expf(-az));
        const float a  = sin_ + bin + r * (shn + bhn);
        const float n  = 2.0f / (1.0f + __expf(-2.0f * a)) - 1.0f;  // tanh, inf-safe
        float hnew = n + z * (hreg - n);
        hnew = (mc > 0.5f) ? hnew : hreg;
        hreg = hnew;

        const __half hf = __float2half(hnew);
        if constexpr (BIG) h16out[(size_t)bt * H_ + lane] = hf;

        // ---- in-wave h broadcast ----
        hsh[t & 1][lane] = hf;
        __syncthreads();                 // single-wave block: just a waitcnt
        {
            const uint4* hp = (const uint4*)hsh[t & 1];
#pragma unroll
            for (int q = 0; q < 8; q++) hq[q].u = hp[q];
        }

        // ---- logits in-loop (small-ws fallback; off recurrence path) ----
        if constexpr (!BIG) {
            float l0 = hnew * wo0, l1 = hnew * wo1;
#pragma unroll
            for (int m = 32; m >= 1; m >>= 1) {
                l0 += __shfl_xor(l0, m, 64);
                l1 += __shfl_xor(l1, m, 64);
            }
            if (lane == 0) *(float2*)(outp + t * 2) = make_float2(l0 + wob0, l1 + wob1);
        }

        // ---- rotate prefetched state ----
        if constexpr (BIG) {
#pragma unroll
            for (int q = 0; q < 8; q++) xpk[q].u = xnp[q].u;
        } else {
#pragma unroll
            for (int q = 0; q < 8; q++) {
                xpk[q].h[0] = pkh2(xnf[2 * q].x, xnf[2 * q].y);
                xpk[q].h[1] = pkh2(xnf[2 * q].z, xnf[2 * q].w);
                xpk[q].h[2] = pkh2(xnf[2 * q + 1].x, xnf[2 * q + 1].y);
                xpk[q].h[3] = pkh2(xnf[2 * q + 1].z, xnf[2 * q + 1].w);
            }
        }
        kc = __builtin_amdgcn_readfirstlane(kn);
        mc = mnb ? 1.0f : 0.0f;
    }
}

extern "C" void kernel_launch(void* const* d_in, const int* in_sizes, int n_in,
                              void* d_out, int out_size, void* d_ws, size_t ws_size,
                              hipStream_t stream) {
    const float* x    = (const float*)d_in[0];
    const int*   ctx  = (const int*)d_in[1];
    const void*  mask = d_in[2];
    const float* W_ir = (const float*)d_in[3];
    const float* W_iz = (const float*)d_in[4];
    const float* W_in = (const float*)d_in[5];
    const float* bir  = (const float*)d_in[6];
    const float* biz  = (const float*)d_in[7];
    const float* bin  = (const float*)d_in[8];
    const float* W_hr = (const float*)d_in[9];
    const float* W_hz = (const float*)d_in[10];
    const float* W_hn = (const float*)d_in[11];
    const float* bhr  = (const float*)d_in[12];
    const float* bhz  = (const float*)d_in[13];
    const float* bhn  = (const float*)d_in[14];
    const float* Wo_w = (const float*)d_in[15];
    const float* Wo_b = (const float*)d_in[16];

    char* ws = (char*)d_ws;
    __half* wh   = (__half*)ws;
    __half* wi   = (__half*)(ws + WS_WI_OFF);
    __half* wo16 = (__half*)(ws + WS_WO_OFF);
    int*    flag = (int*)(ws + WS_FLAG_OFF);
    __half* xh16 = (__half*)(ws + WS_XH_OFF);
    __half* h16  = (__half*)(ws + WS_H16_OFF);

    const bool big = (ws_size >= WS_BIG_NEED);

    detect_mask_kernel<<<1, 256, 0, stream>>>((const unsigned char*)mask, flag);
    convert_weights_kernel<<<192, 256, 0, stream>>>(W_hr, W_hz, W_hn, W_ir, W_iz, W_in,
                                                    Wo_w, wh, wi, wo16);
    if (big) {
        convert_x_kernel<<<8192, 256, 0, stream>>>(x, xh16);
        gru_seq<true><<<B_, 64, 0, stream>>>(x, xh16, ctx, (const unsigned char*)mask, flag,
                                             wh, wi, bir, biz, bin, bhr, bhz, bhn,
                                             Wo_w, Wo_b, h16, (float*)d_out);
        logits_kernel<<<(B_ * T_) / 256, 256, 0, stream>>>(h16, wo16, Wo_b, (float*)d_out);
    } else {
        gru_seq<false><<<B_, 64, 0, stream>>>(x, xh16, ctx, (const unsigned char*)mask, flag,
                                              wh, wi, bir, biz, bin, bhr, bhz, bhn,
                                              Wo_w, Wo_b, h16, (float*)d_out);
    }
}

// Round 7
// 711.629 us; speedup vs baseline: 1.5355x; 1.5355x over previous
//
#include <hip/hip_runtime.h>
#include <hip/hip_fp16.h>

#define B_ 512
#define T_ 512
#define H_ 64
#define K_ 4

// ws layout:
//   wht  f16 [K*3][8 chunks][64 rows][8]  @ 0       (98304 B)   transposed-chunk
//   wit  f16 [3][8][64][8]               @ 98304    (24576 B)   transposed-chunk
//   wo16 f16 [2*H]                       @ 122880   (256 B)
//   flag int                             @ 123136
//   xh16 f16 [B*T*H]                     @ 131072   (33554432 B) [BIG]
//   h16  f16 [B*T*H]                     @ 33685504 (33554432 B) [BIG]
#define WS_WIT_OFF   98304
#define WS_WO_OFF    122880
#define WS_FLAG_OFF  123136
#define WS_XH_OFF    131072
#define WS_H16_OFF   33685504
#define WS_BIG_NEED  67239936ull

// dynamic LDS map: staged weights [0,122880) ; h scratch @122880 (2 waves x 2 bufs x 128 B)
#define LDS_H_OFF    122880
#define LDS_TOTAL    123392
#define STAGE_U4     7680      // 122880 / 16

typedef _Float16 half2_t __attribute__((ext_vector_type(2)));

union Q { uint4 u; half2_t h[4]; };  // 16 B = 4 packed half2

__device__ __forceinline__ float fdot2f(half2_t a, half2_t b, float c) {
#if __has_builtin(__builtin_amdgcn_fdot2)
    return __builtin_amdgcn_fdot2(a, b, c, false);
#else
    return fmaf((float)a[0], (float)b[0], fmaf((float)a[1], (float)b[1], c));
#endif
}

__device__ __forceinline__ half2_t pkh2(float a, float b) {
    return __builtin_bit_cast(half2_t, __builtin_amdgcn_cvt_pkrtz(a, b));
}

// Detect whether mask buffer is 1-byte bools or int32 0/1 (little-endian).
__global__ void detect_mask_kernel(const unsigned char* __restrict__ mb, int* __restrict__ flag) {
    __shared__ int cnt;
    if (threadIdx.x == 0) cnt = 0;
    __syncthreads();
    int c = 0;
    for (int i = threadIdx.x; i < 4096; i += blockDim.x)
        if ((i & 3) != 0 && mb[i] != 0) c++;
    atomicAdd(&cnt, c);
    __syncthreads();
    if (threadIdx.x == 0) *flag = (cnt > 0) ? 1 : 0;  // 1 => uint8 bools, 0 => int32
}

// Weights -> f16 transposed-chunk layout: dst[((mat*8 + (j>>3))*64 + i)*8 + (j&7)]
__global__ void convert_weights_kernel(const float* __restrict__ Whr, const float* __restrict__ Whz,
                                       const float* __restrict__ Whn, const float* __restrict__ Wir,
                                       const float* __restrict__ Wiz, const float* __restrict__ Win,
                                       const float* __restrict__ Wo,
                                       __half* __restrict__ wht, __half* __restrict__ wit,
                                       __half* __restrict__ wo16) {
    int idx = blockIdx.x * 256 + threadIdx.x;
    if (idx < K_ * 3 * H_ * H_) {
        int mat = idx >> 12;            // k*3+g
        int i   = (idx >> 6) & 63;
        int j   = idx & 63;
        int k   = mat / 3, g = mat - 3 * k;
        const float* src = (g == 0) ? Whr : (g == 1) ? Whz : Whn;
        int dst = ((mat * 8 + (j >> 3)) * 64 + i) * 8 + (j & 7);
        wht[dst] = __float2half(src[(k * H_ + i) * H_ + j]);
    }
    if (idx < 3 * H_ * H_) {
        int g = idx >> 12;
        int i = (idx >> 6) & 63;
        int j = idx & 63;
        const float* src = (g == 0) ? Wir : (g == 1) ? Wiz : Win;
        int dst = ((g * 8 + (j >> 3)) * 64 + i) * 8 + (j & 7);
        wit[dst] = __float2half(src[i * H_ + j]);
    }
    if (idx < 2 * H_) wo16[idx] = __float2half(Wo[idx]);
}

// x f32 -> packed f16
__global__ void convert_x_kernel(const float* __restrict__ xf, __half* __restrict__ xh) {
    size_t i = (size_t)blockIdx.x * 256 + threadIdx.x;
    if (i >= (size_t)B_ * T_ * H_ / 8) return;
    const float4* p = (const float4*)xf + 2 * i;
    float4 a = p[0], b = p[1];
    Q o;
    o.h[0] = pkh2(a.x, a.y);
    o.h[1] = pkh2(a.z, a.w);
    o.h[2] = pkh2(b.x, b.y);
    o.h[3] = pkh2(b.z, b.w);
    ((uint4*)xh)[i] = o.u;
}

// Parallel logits: one thread per (b,t)
__global__ __launch_bounds__(256)
void logits_kernel(const __half* __restrict__ h16, const __half* __restrict__ wo16,
                   const float* __restrict__ Wo_b, float* __restrict__ out) {
    const int idx = blockIdx.x * 256 + threadIdx.x;
    Q w0[8], w1[8], hv[8];
    const uint4* wp = (const uint4*)wo16;
#pragma unroll
    for (int q = 0; q < 8; q++) { w0[q].u = wp[q]; w1[q].u = wp[8 + q]; }
    const uint4* hp = (const uint4*)(h16 + (size_t)idx * H_);
#pragma unroll
    for (int q = 0; q < 8; q++) hv[q].u = hp[q];
    float l0 = Wo_b[0], l1 = Wo_b[1];
#pragma unroll
    for (int q = 0; q < 8; q++)
#pragma unroll
        for (int p = 0; p < 4; p++) {
            l0 = fdot2f(w0[q].h[p], hv[q].h[p], l0);
            l1 = fdot2f(w1[q].h[p], hv[q].h[p], l1);
        }
    ((float2*)out)[idx] = make_float2(l0, l1);
}

// Sequential GRU. 128-thread block = 2 independent waves = 2 batch elements.
// ALL weights (4 experts W_h + W_i, f16, 120 KB) live in LDS, staged once.
// No __syncthreads in the loop; each wave's h broadcast uses its own LDS
// scratch (same-wave in-order DS pipe + wave_barrier + double buffer).
// lane = output row i; 192 fdot2/step; weight ds_read_b128 are conflict-free
// (transposed-chunk layout: consecutive lanes read consecutive 16 B).
template <bool BIG>
__global__ __launch_bounds__(128, 1)
void gru_seq2(const float* __restrict__ xf, const __half* __restrict__ xh16,
              const int* __restrict__ ctx, const unsigned char* __restrict__ maskb,
              const int* __restrict__ flagp, const __half* __restrict__ wstaged,
              const float* __restrict__ b_ir, const float* __restrict__ b_iz,
              const float* __restrict__ b_in, const float* __restrict__ b_hr,
              const float* __restrict__ b_hz, const float* __restrict__ b_hn,
              const float* __restrict__ Wo_w, const float* __restrict__ Wo_b,
              __half* __restrict__ h16out, float* __restrict__ out) {
    extern __shared__ __align__(16) char smem[];
    uint4* sw = (uint4*)smem;

    const int tid  = threadIdx.x;
    const int lane = tid & 63;
    const int wv   = tid >> 6;            // 0,1
    const int b    = blockIdx.x * 2 + wv;

    // ---- cooperative weight staging (global -> LDS), once ----
    {
        const uint4* gsrc = (const uint4*)wstaged;
#pragma unroll 1
        for (int i = tid; i < STAGE_U4; i += 128) sw[i] = gsrc[i];
    }
    __syncthreads();

    const int flag   = *flagp;
    const int mshift = flag ? 0 : 2;
    const int bt0    = b * T_;

    const float bir = b_ir[lane], biz = b_iz[lane], bin = b_in[lane];
    float wo0 = 0.f, wo1 = 0.f, wob0 = 0.f, wob1 = 0.f;
    if constexpr (!BIG) {
        wo0 = Wo_w[lane]; wo1 = Wo_w[64 + lane]; wob0 = Wo_b[0]; wob1 = Wo_b[1];
    }

    float hreg = 0.0f;
    Q hq[8];
#pragma unroll
    for (int q = 0; q < 8; q++) hq[q].u = make_uint4(0u, 0u, 0u, 0u);

    // per-wave h scratch (double-buffered), no cross-wave sharing
    __half* hsc = (__half*)(smem + LDS_H_OFF + (wv << 8));

    // W_i LDS base (uint4 index): 6144 + g*512 + q*64 + lane
    const uint4* wip = sw + 6144 + lane;

    // ---- prologue: x(0), ctx(0), mask(0) ----
    Q xpk[8];
    if constexpr (BIG) {
        const uint4* xp = (const uint4*)(xh16 + (size_t)bt0 * H_);
#pragma unroll
        for (int q = 0; q < 8; q++) xpk[q].u = xp[q];
    } else {
        const float4* xp = (const float4*)(xf + (size_t)bt0 * H_);
#pragma unroll
        for (int q = 0; q < 8; q++) {
            float4 a = xp[2 * q], c = xp[2 * q + 1];
            xpk[q].h[0] = pkh2(a.x, a.y);
            xpk[q].h[1] = pkh2(a.z, a.w);
            xpk[q].h[2] = pkh2(c.x, c.y);
            xpk[q].h[3] = pkh2(c.z, c.w);
        }
    }
    int   kc = __builtin_amdgcn_readfirstlane(ctx[bt0]);
    float mc = maskb[(size_t)bt0 << mshift] ? 1.0f : 0.0f;

    float* outp = out + (size_t)b * T_ * 2;

#pragma unroll 1
    for (int t = 0; t < T_; t++) {
        const int bt  = bt0 + t;
        const int tn  = (t + 1 < T_) ? (t + 1) : t;
        const int btn = bt0 + tn;

        // ---- W_h[kc] from LDS (24 conflict-free ds_read_b128) ----
        const uint4* whp = sw + kc * 1536 + lane;
        Q whrq[8], whzq[8], whnq[8];
#pragma unroll
        for (int q = 0; q < 8; q++) {
            whrq[q].u = whp[q * 64];
            whzq[q].u = whp[512 + q * 64];
            whnq[q].u = whp[1024 + q * 64];
        }
        // biases for kc (tiny, L1)
        const float bhr = b_hr[kc * H_ + lane];
        const float bhz = b_hz[kc * H_ + lane];
        const float bhn = b_hn[kc * H_ + lane];

        // ---- prefetch t+1 inputs ----
        Q xnp[8];
        float4 xnf[16];
        if constexpr (BIG) {
            const uint4* xp = (const uint4*)(xh16 + (size_t)btn * H_);
#pragma unroll
            for (int q = 0; q < 8; q++) xnp[q].u = xp[q];
        } else {
            const float4* xp = (const float4*)(xf + (size_t)btn * H_);
#pragma unroll
            for (int q = 0; q < 16; q++) xnf[q] = xp[q];
        }
        int           kn  = ctx[btn];
        unsigned char mnb = maskb[(size_t)btn << mshift];

        // ---- input projection from LDS W_i (h-independent) ----
        float sir = 0.f, siz = 0.f, sin_ = 0.f;
#pragma unroll
        for (int q = 0; q < 8; q++) {
            Q wr, wz, wn;
            wr.u = wip[q * 64];
            wz.u = wip[512 + q * 64];
            wn.u = wip[1024 + q * 64];
#pragma unroll
            for (int p = 0; p < 4; p++) {
                sir  = fdot2f(wr.h[p], xpk[q].h[p], sir);
                siz  = fdot2f(wz.h[p], xpk[q].h[p], siz);
                sin_ = fdot2f(wn.h[p], xpk[q].h[p], sin_);
            }
        }

        // ---- hidden matvec (96 fdot2) ----
        float shr = 0.f, shz = 0.f, shn = 0.f;
#pragma unroll
        for (int q = 0; q < 8; q++)
#pragma unroll
            for (int p = 0; p < 4; p++) {
                shr = fdot2f(whrq[q].h[p], hq[q].h[p], shr);
                shz = fdot2f(whzq[q].h[p], hq[q].h[p], shz);
                shn = fdot2f(whnq[q].h[p], hq[q].h[p], shn);
            }

        // ---- epilogue (in-lane) ----
        const float ar = sir + shr + bir + bhr;
        const float az = siz + shz + biz + bhz;
        const float r  = 1.0f / (1.0f + __expf(-ar));
        const float z  = 1.0f / (1.0f + __expf(-az));
        const float a  = sin_ + bin + r * (shn + bhn);
        const float n  = 2.0f / (1.0f + __expf(-2.0f * a)) - 1.0f;  // tanh, inf-safe
        float hnew = n + z * (hreg - n);
        hnew = (mc > 0.5f) ? hnew : hreg;
        hreg = hnew;

        const __half hf = __float2half(hnew);
        if constexpr (BIG) h16out[(size_t)bt * H_ + lane] = hf;

        // ---- same-wave h broadcast (double-buffered, order pinned) ----
        __half* hb = hsc + ((t & 1) << 6);
        hb[lane] = hf;
        __builtin_amdgcn_wave_barrier();
        {
            const uint4* hp = (const uint4*)hb;
#pragma unroll
            for (int q = 0; q < 8; q++) hq[q].u = hp[q];
        }
        __builtin_amdgcn_wave_barrier();

        // ---- logits in-loop (fallback path only) ----
        if constexpr (!BIG) {
            float l0 = hnew * wo0, l1 = hnew * wo1;
#pragma unroll
            for (int m = 32; m >= 1; m >>= 1) {
                l0 += __shfl_xor(l0, m, 64);
                l1 += __shfl_xor(l1, m, 64);
            }
            if (lane == 0) *(float2*)(outp + t * 2) = make_float2(l0 + wob0, l1 + wob1);
        }

        // ---- rotate prefetched state ----
        if constexpr (BIG) {
#pragma unroll
            for (int q = 0; q < 8; q++) xpk[q].u = xnp[q].u;
        } else {
#pragma unroll
            for (int q = 0; q < 8; q++) {
                xpk[q].h[0] = pkh2(xnf[2 * q].x, xnf[2 * q].y);
                xpk[q].h[1] = pkh2(xnf[2 * q].z, xnf[2 * q].w);
                xpk[q].h[2] = pkh2(xnf[2 * q + 1].x, xnf[2 * q + 1].y);
                xpk[q].h[3] = pkh2(xnf[2 * q + 1].z, xnf[2 * q + 1].w);
            }
        }
        kc = __builtin_amdgcn_readfirstlane(kn);
        mc = mnb ? 1.0f : 0.0f;
    }
}

extern "C" void kernel_launch(void* const* d_in, const int* in_sizes, int n_in,
                              void* d_out, int out_size, void* d_ws, size_t ws_size,
                              hipStream_t stream) {
    const float* x    = (const float*)d_in[0];
    const int*   ctx  = (const int*)d_in[1];
    const void*  mask = d_in[2];
    const float* W_ir = (const float*)d_in[3];
    const float* W_iz = (const float*)d_in[4];
    const float* W_in = (const float*)d_in[5];
    const float* bir  = (const float*)d_in[6];
    const float* biz  = (const float*)d_in[7];
    const float* bin  = (const float*)d_in[8];
    const float* W_hr = (const float*)d_in[9];
    const float* W_hz = (const float*)d_in[10];
    const float* W_hn = (const float*)d_in[11];
    const float* bhr  = (const float*)d_in[12];
    const float* bhz  = (const float*)d_in[13];
    const float* bhn  = (const float*)d_in[14];
    const float* Wo_w = (const float*)d_in[15];
    const float* Wo_b = (const float*)d_in[16];

    char* ws = (char*)d_ws;
    __half* wht  = (__half*)ws;
    __half* wit  = (__half*)(ws + WS_WIT_OFF);
    __half* wo16 = (__half*)(ws + WS_WO_OFF);
    int*    flag = (int*)(ws + WS_FLAG_OFF);
    __half* xh16 = (__half*)(ws + WS_XH_OFF);
    __half* h16  = (__half*)(ws + WS_H16_OFF);

    const bool big = (ws_size >= WS_BIG_NEED);

    detect_mask_kernel<<<1, 256, 0, stream>>>((const unsigned char*)mask, flag);
    convert_weights_kernel<<<192, 256, 0, stream>>>(W_hr, W_hz, W_hn, W_ir, W_iz, W_in,
                                                    Wo_w, wht, wit, wo16);
    if (big) {
        convert_x_kernel<<<8192, 256, 0, stream>>>(x, xh16);
        (void)hipFuncSetAttribute((const void*)gru_seq2<true>,
                                  hipFuncAttributeMaxDynamicSharedMemorySize, LDS_TOTAL);
        gru_seq2<true><<<B_ / 2, 128, LDS_TOTAL, stream>>>(
            x, xh16, ctx, (const unsigned char*)mask, flag, wht,
            bir, biz, bin, bhr, bhz, bhn, Wo_w, Wo_b, h16, (float*)d_out);
        logits_kernel<<<(B_ * T_) / 256, 256, 0, stream>>>(h16, wo16, Wo_b, (float*)d_out);
    } else {
        (void)hipFuncSetAttribute((const void*)gru_seq2<false>,
                                  hipFuncAttributeMaxDynamicSharedMemorySize, LDS_TOTAL);
        gru_seq2<false><<<B_ / 2, 128, LDS_TOTAL, stream>>>(
            x, xh16, ctx, (const unsigned char*)mask, flag, wht,
            bir, biz, bin, bhr, bhz, bhn, Wo_w, Wo_b, h16, (float*)d_out);
    }
}